// Round 3
// baseline (643.657 us; speedup 1.0000x reference)
//
#include <hip/hip_runtime.h>
#include <hip/hip_bf16.h>

#define B_ 16
#define N_ 2048
#define D_ 64

typedef __bf16 bf16x8 __attribute__((ext_vector_type(8)));
typedef __bf16 bf16x4 __attribute__((ext_vector_type(4)));
typedef float  f32x4  __attribute__((ext_vector_type(4)));
typedef float  f32x16 __attribute__((ext_vector_type(16)));

// load 8 bf16 from an 8B-aligned LDS address (two b64 reads)
static __device__ __forceinline__ bf16x8 ld_frag(const __bf16* p) {
  bf16x4 lo = *(const bf16x4*)p;
  bf16x4 hi = *(const bf16x4*)(p + 4);
  return __builtin_shufflevector(lo, hi, 0, 1, 2, 3, 4, 5, 6, 7);
}

// direct global->frag: 8 consecutive fp32 at p, converted to bf16x8
static __device__ __forceinline__ bf16x8 load_frag_g(const float* p) {
  f32x4 a = *(const f32x4*)p;
  f32x4 b = *(const f32x4*)(p + 4);
  bf16x8 w;
#pragma unroll
  for (int i = 0; i < 4; ++i) {
    w[i]     = (__bf16)a[i];
    w[i + 4] = (__bf16)b[i];
  }
  return w;
}

__global__ __launch_bounds__(256, 2)
void General_Attention_62251255988379_kernel(const float* __restrict__ Q,
                                             const float* __restrict__ K,
                                             const float* __restrict__ V,
                                             float* __restrict__ out) {
  __shared__ __bf16 PtW[4 * 32 * 36];  // per-wave P slab [32 rows][36], stride 36
  __shared__ float  lsum[64];
  __shared__ float  Ored[64 * 64];     // cross-wave O reduction scratch

  const int tid  = threadIdx.x;
  const int blk  = blockIdx.x;
  const int bb   = blk & 15;                       // batch; all 32 row-blocks of a
  const int u    = blk >> 4;                       // batch share one XCD (%8 map)
  const int rb   = (u < 16) ? (31 - u) : (u - 16); // heavy first; pair = const work
  const int row0 = rb * 64;
  const int lane = tid & 63;
  const int wave = tid >> 6;
  const int wr   = wave & 1;
  const int wc   = wave >> 1;
  const int ln   = lane & 31;
  const int half = lane >> 5;

  const float* Qb = Q + (size_t)bb * N_ * D_;
  const float* Kb = K + (size_t)bb * N_ * D_;
  const float* Vb = V + (size_t)bb * N_ * D_;
  float* Ob = out + (size_t)bb * N_ * D_;
  float* Ab = out + (size_t)B_ * N_ * D_ + (size_t)bb * N_ * N_;

  if (tid < 64) lsum[tid] = 0.0f;
  __syncthreads();  // barrier 1: lsum init visible before any atomicAdd

  // ---- Q frags direct from global, pre-scaled by 1/sqrt(D)=0.125 ----
  const float* qbase = Qb + (size_t)(row0 + 32 * wr + ln) * D_ + half * 8;
  bf16x8 qf[4];
#pragma unroll
  for (int kk = 0; kk < 4; ++kk) {
    f32x4 a = *(const f32x4*)(qbase + 16 * kk);
    f32x4 b = *(const f32x4*)(qbase + 16 * kk + 4);
#pragma unroll
    for (int i = 0; i < 4; ++i) {
      qf[kk][i]     = (__bf16)(a[i] * 0.125f);
      qf[kk][i + 4] = (__bf16)(b[i] * 0.125f);
    }
  }

  const float* kbase = Kb + (size_t)(32 * wc + ln) * D_ + half * 8;

  // ===================== pass A: row sums of exp(s) — no barriers ============
  float sums[16];
#pragma unroll
  for (int r = 0; r < 16; ++r) sums[r] = 0.0f;

#pragma unroll 1
  for (int ct = 0; ct <= rb; ++ct) {
    const float* kp = kbase + (size_t)ct * 64 * D_;
    bf16x8 kf[4];
#pragma unroll
    for (int kk = 0; kk < 4; ++kk) kf[kk] = load_frag_g(kp + 16 * kk);

    f32x16 s;
#pragma unroll
    for (int i = 0; i < 16; ++i) s[i] = 0.0f;
#pragma unroll
    for (int kk = 0; kk < 4; ++kk)
      s = __builtin_amdgcn_mfma_f32_32x32x16_bf16(qf[kk], kf[kk], s, 0, 0, 0);

    const bool diag = (ct == rb);
#pragma unroll
    for (int r = 0; r < 16; ++r) {
      float e = __expf(s[r]);
      if (diag) {
        const int ro = (r & 3) + 8 * (r >> 2) + 4 * half;
        e = ((32 * wc + ln) <= (32 * wr + ro)) ? e : 0.0f;
      }
      sums[r] += e;
    }
  }

  // butterfly-reduce across the 32 lanes holding each row's columns
#pragma unroll
  for (int r = 0; r < 16; ++r) {
    float v = sums[r];
    v += __shfl_xor(v, 1);
    v += __shfl_xor(v, 2);
    v += __shfl_xor(v, 4);
    v += __shfl_xor(v, 8);
    v += __shfl_xor(v, 16);
    sums[r] = v;
  }
  if (ln == 0) {
#pragma unroll
    for (int r = 0; r < 16; ++r) {
      const int ro = (r & 3) + 8 * (r >> 2) + 4 * half;
      atomicAdd(&lsum[32 * wr + ro], sums[r]);
    }
  }
  __syncthreads();  // barrier 2: all row sums complete

  float linv[16];
#pragma unroll
  for (int r = 0; r < 16; ++r) {
    const int ro = (r & 3) + 8 * (r >> 2) + 4 * half;
    linv[r] = 1.0f / lsum[32 * wr + ro];
  }

  // ============ pass B: att writes + O = P.V — no per-tile barriers ==========
  f32x16 o0, o1;
#pragma unroll
  for (int i = 0; i < 16; ++i) { o0[i] = 0.0f; o1[i] = 0.0f; }
  __bf16* Pt = &PtW[wave * 32 * 36];

  // V column base: lane ln -> d=ln (o0) / d=ln+32 (o1); k rows walk by stride D
  const float* vcol0 = Vb + (size_t)(32 * wc + 8 * half) * D_ + ln;

#pragma unroll 1
  for (int ct = 0; ct <= rb; ++ct) {
    const int c0 = ct * 64;

    // V loads first (independent of S chain); coalesced 128B segments per j
    const float* vp = vcol0 + (size_t)ct * 64 * D_;
    float va[16], vb2[16];
#pragma unroll
    for (int kk2 = 0; kk2 < 2; ++kk2)
#pragma unroll
      for (int j = 0; j < 8; ++j) {
        va[kk2 * 8 + j]  = vp[(size_t)(16 * kk2 + j) * D_];
        vb2[kk2 * 8 + j] = vp[(size_t)(16 * kk2 + j) * D_ + 32];
      }

    // K frags + S = Q.K^T
    const float* kp = kbase + (size_t)ct * 64 * D_;
    bf16x8 kf[4];
#pragma unroll
    for (int kk = 0; kk < 4; ++kk) kf[kk] = load_frag_g(kp + 16 * kk);

    f32x16 s;
#pragma unroll
    for (int i = 0; i < 16; ++i) s[i] = 0.0f;
#pragma unroll
    for (int kk = 0; kk < 4; ++kk)
      s = __builtin_amdgcn_mfma_f32_32x32x16_bf16(qf[kk], kf[kk], s, 0, 0, 0);

    const bool diag = (ct == rb);
#pragma unroll
    for (int r = 0; r < 16; ++r) {
      const int ro = (r & 3) + 8 * (r >> 2) + 4 * half;
      float e = __expf(s[r]);
      if (diag) e = ((32 * wc + ln) <= (32 * wr + ro)) ? e : 0.0f;
      const float pv = e * linv[r];
      __builtin_nontemporal_store(pv,
          Ab + (size_t)(row0 + 32 * wr + ro) * N_ + c0 + 32 * wc + ln);
      Pt[ro * 36 + ln] = (__bf16)pv;   // wave-private: same-wave lgkm ordering
    }

    // O partial over this wave's 32 k-columns
#pragma unroll
    for (int kk2 = 0; kk2 < 2; ++kk2) {
      bf16x8 af = ld_frag(&Pt[ln * 36 + 16 * kk2 + 8 * half]);
      bf16x8 b0, b1;
#pragma unroll
      for (int j = 0; j < 8; ++j) {
        b0[j] = (__bf16)va[kk2 * 8 + j];
        b1[j] = (__bf16)vb2[kk2 * 8 + j];
      }
      o0 = __builtin_amdgcn_mfma_f32_32x32x16_bf16(af, b0, o0, 0, 0, 0);
      o1 = __builtin_amdgcn_mfma_f32_32x32x16_bf16(af, b1, o1, 0, 0, 0);
    }
  }

  // ---- cross-wave O reduction (wc=1 partials -> wc=0) and store ----
  if (wc == 1) {
#pragma unroll
    for (int r = 0; r < 16; ++r) {
      const int ro = (r & 3) + 8 * (r >> 2) + 4 * half;
      Ored[(32 * wr + ro) * 64 + ln]      = o0[r];
      Ored[(32 * wr + ro) * 64 + 32 + ln] = o1[r];
    }
  }
  __syncthreads();  // barrier 3
  if (wc == 0) {
#pragma unroll
    for (int r = 0; r < 16; ++r) {
      const int ro = (r & 3) + 8 * (r >> 2) + 4 * half;
      float* op = Ob + (size_t)(row0 + 32 * wr + ro) * D_;
      __builtin_nontemporal_store(o0[r] + Ored[(32 * wr + ro) * 64 + ln], op + ln);
      __builtin_nontemporal_store(o1[r] + Ored[(32 * wr + ro) * 64 + 32 + ln], op + 32 + ln);
    }
  }

  // ---- zero-fill strictly-upper columns of att for this row tile ----
  const int cz0 = 64 * (rb + 1);
  if (cz0 < N_) {
    f32x4 z = {0.0f, 0.0f, 0.0f, 0.0f};
#pragma unroll 1
    for (int rr = (tid >> 6); rr < 64; rr += 4) {
      float* rowp = Ab + (size_t)(row0 + rr) * N_;
      for (int x = cz0 + (tid & 63) * 4; x < N_; x += 256)
        __builtin_nontemporal_store(z, (f32x4*)(rowp + x));
    }
  }
}

extern "C" void kernel_launch(void* const* d_in, const int* in_sizes, int n_in,
                              void* d_out, int out_size, void* d_ws, size_t ws_size,
                              hipStream_t stream) {
  const float* Q = (const float*)d_in[0];
  const float* K = (const float*)d_in[1];
  const float* V = (const float*)d_in[2];
  (void)in_sizes; (void)n_in; (void)out_size; (void)d_ws; (void)ws_size;
  float* out = (float*)d_out;
  General_Attention_62251255988379_kernel<<<dim3(512), dim3(256), 0, stream>>>(Q, K, V, out);
}